// Round 5
// baseline (1003.818 us; speedup 1.0000x reference)
//
#include <hip/hip_runtime.h>

#define THREADS 256
#define SCAN_ITEMS 8   // 2048 elements per scan block

typedef float f32x4 __attribute__((ext_vector_type(4)));
typedef __bf16 bf16x8 __attribute__((ext_vector_type(8)));
typedef int intx4 __attribute__((ext_vector_type(4)));

__device__ inline unsigned short f32_to_bf16_rne(float f) {
    unsigned int u = __float_as_uint(f);
    unsigned int r = u + 0x7fffu + ((u >> 16) & 1u);
    return (unsigned short)(r >> 16);
}
__device__ inline float bf16_bits_to_f32(unsigned short h) {
    return __uint_as_float(((unsigned int)h) << 16);
}
__device__ inline uint4 pack8(const unsigned short* s) {
    uint4 u;
    u.x = (unsigned int)s[0] | ((unsigned int)s[1] << 16);
    u.y = (unsigned int)s[2] | ((unsigned int)s[3] << 16);
    u.z = (unsigned int)s[4] | ((unsigned int)s[5] << 16);
    u.w = (unsigned int)s[6] | ((unsigned int)s[7] << 16);
    return u;
}

// Physical XCD id (gfx940+: hwreg 20 = HW_REG_XCC_ID, bits [3:0]).
// Used only as a locality hint — work-stealing below guarantees coverage
// regardless of what this returns.
__device__ inline int xcc_id() {
    unsigned v;
    asm volatile("s_getreg_b32 %0, hwreg(20, 0, 4)" : "=s"(v));
    return (int)(v & 7u);
}

// ---------------- CSR build ----------------
__global__ void zero_int(int* __restrict__ p, int n) {
    int i = blockIdx.x * blockDim.x + threadIdx.x;
    if (i < n) p[i] = 0;
}

// XCD-pinned sliced histogram with work-stealing. Slice g owns dst nodes with
// (d>>12)&7 == g (~64 KB cnt window). Blocks claim 1024-edge chunks of their
// own XCD's slice via cursors[g]; after exhaustion they steal other slices,
// so every edge is processed no matter how blocks map to XCDs.
__global__ __launch_bounds__(256) void degree_xcd(const int* __restrict__ dst,
                                                  int* __restrict__ cnt,
                                                  int* __restrict__ cursors, int E) {
    __shared__ int s_base;
    const int tid = threadIdx.x;
    const int g0 = xcc_id();
    for (int gi = 0; gi < 8; gi++) {
        int g = (g0 + gi) & 7;
        for (;;) {
            if (tid == 0) s_base = atomicAdd(&cursors[g], 1024);
            __syncthreads();
            int base = s_base;
            __syncthreads();
            if (base >= E) break;
            int i = base + tid * 4;
            if (i + 4 <= E) {
                intx4 d4 = *(const intx4*)(dst + i);
#pragma unroll
                for (int k = 0; k < 4; k++) {
                    int d = d4[k];
                    if (((d >> 12) & 7) == g) atomicAdd(&cnt[d], 1);
                }
            } else {
                for (int e = i; e < E; e++) {
                    int d = dst[e];
                    if (((d >> 12) & 7) == g) atomicAdd(&cnt[d], 1);
                }
            }
        }
    }
}

__global__ void scan1_kernel(const int* __restrict__ cnt, int* __restrict__ off,
                             int* __restrict__ bsums, int n) {
    __shared__ int sdata[THREADS];
    int base = blockIdx.x * (THREADS * SCAN_ITEMS) + threadIdx.x * SCAN_ITEMS;
    int vals[SCAN_ITEMS];
    int tsum = 0;
#pragma unroll
    for (int k = 0; k < SCAN_ITEMS; k++) {
        int idx = base + k;
        int v = (idx < n) ? cnt[idx] : 0;
        vals[k] = tsum;
        tsum += v;
    }
    sdata[threadIdx.x] = tsum;
    __syncthreads();
    for (int s = 1; s < THREADS; s <<= 1) {
        int y = (threadIdx.x >= (unsigned)s) ? sdata[threadIdx.x - s] : 0;
        __syncthreads();
        sdata[threadIdx.x] += y;
        __syncthreads();
    }
    int texcl = sdata[threadIdx.x] - tsum;
#pragma unroll
    for (int k = 0; k < SCAN_ITEMS; k++) {
        int idx = base + k;
        if (idx < n) off[idx] = texcl + vals[k];
    }
    if (threadIdx.x == THREADS - 1) bsums[blockIdx.x] = sdata[THREADS - 1];
}

__global__ void scan2_kernel(const int* __restrict__ bsums, int* __restrict__ bbase,
                             int nb, int* __restrict__ offN) {
    if (threadIdx.x == 0 && blockIdx.x == 0) {
        int run = 0;
        for (int i = 0; i < nb; i++) { bbase[i] = run; run += bsums[i]; }
        *offN = run;
    }
}

__global__ void scan3_kernel(int* __restrict__ off, int* __restrict__ pos,
                             const int* __restrict__ bbase, int n) {
    int i = blockIdx.x * blockDim.x + threadIdx.x;
    if (i < n) {
        int v = off[i] + bbase[i >> 11];
        off[i] = v;
        pos[i] = v;
    }
}

// XCD-pinned bucket fill: slice g's ~850 KB pos+srcs window is written only by
// blocks physically on XCD g, so lines fill completely in that L2 before a
// single writeback (vs cross-XCD partial-line ping-pong).
__global__ __launch_bounds__(256) void bucket_xcd(const int* __restrict__ src,
                                                  const int* __restrict__ dst,
                                                  int* __restrict__ pos,
                                                  int* __restrict__ srcs,
                                                  int* __restrict__ cursors, int E) {
    __shared__ int s_base;
    const int tid = threadIdx.x;
    const int g0 = xcc_id();
    for (int gi = 0; gi < 8; gi++) {
        int g = (g0 + gi) & 7;
        for (;;) {
            if (tid == 0) s_base = atomicAdd(&cursors[g], 1024);
            __syncthreads();
            int base = s_base;
            __syncthreads();
            if (base >= E) break;
            int i = base + tid * 4;
            if (i + 4 <= E) {
                intx4 d4 = *(const intx4*)(dst + i);
                intx4 s4 = *(const intx4*)(src + i);
#pragma unroll
                for (int k = 0; k < 4; k++) {
                    int d = d4[k];
                    if (((d >> 12) & 7) == g) {
                        int p = atomicAdd(&pos[d], 1);
                        srcs[p] = s4[k];
                    }
                }
            } else {
                for (int e = i; e < E; e++) {
                    int d = dst[e];
                    if (((d >> 12) & 7) == g) {
                        int p = atomicAdd(&pos[d], 1);
                        srcs[p] = src[e];
                    }
                }
            }
        }
    }
}

// ---------------- precision prep ----------------
__global__ void cvt_bf16_kernel(const float4* __restrict__ x, ushort4* __restrict__ o, int n4) {
    int i = blockIdx.x * blockDim.x + threadIdx.x;
    if (i < n4) {
        float4 v = x[i];
        ushort4 r;
        r.x = f32_to_bf16_rne(v.x);
        r.y = f32_to_bf16_rne(v.y);
        r.z = f32_to_bf16_rne(v.z);
        r.w = f32_to_bf16_rne(v.w);
        o[i] = r;
    }
}

// Swizzled hi/lo bf16 weights. W256[k][n]: k<128 -> Wn, else Wr.
// [t(8)][nt(8)][plane(2)][lane(64)] x 16B; B frag: n = lane&15, k = t*32+(lane>>4)*8+j.
__global__ void swizzle_w_kernel(const float* __restrict__ Wn, const float* __restrict__ Wr,
                                 uint4* __restrict__ out) {
    int id = blockIdx.x * blockDim.x + threadIdx.x;
    if (id >= 4096) return;
    int lane = id & 63;
    int nt = (id >> 6) & 7;
    int t = id >> 9;
    int kbase = t * 32 + (lane >> 4) * 8;
    int col = nt * 16 + (lane & 15);
    unsigned short hi[8], lo[8];
#pragma unroll
    for (int j = 0; j < 8; j++) {
        int k = kbase + j;
        const float* W = (k < 128) ? (Wn + (size_t)k * 128) : (Wr + (size_t)(k - 128) * 128);
        float v = W[col];
        unsigned short h = f32_to_bf16_rne(v);
        hi[j] = h;
        lo[j] = f32_to_bf16_rne(v - bf16_bits_to_f32(h));
    }
    out[(size_t)((t * 8 + nt) * 2 + 0) * 64 + lane] = pack8(hi);
    out[(size_t)((t * 8 + nt) * 2 + 1) * 64 + lane] = pack8(lo);
}

// ---------------- aggregation (bf16 gather, fp32 acc, bf16 out) ----------------
// One wave per node. Lane-distributed srcs prefetch + 8-wide gather unroll.
__global__ void agg_kernel(const unsigned short* __restrict__ hb, const int* __restrict__ off,
                           const int* __restrict__ srcs, unsigned short* __restrict__ aggb,
                           int n) {
    int gid = blockIdx.x * blockDim.x + threadIdx.x;
    int node = gid >> 6;
    int lane = threadIdx.x & 63;
    if (node >= n) return;
    int p0 = off[node], p1 = off[node + 1];
    int deg = p1 - p0;
    float ax = 0.f, ay = 0.f;
    for (int base = 0; base < deg; base += 64) {
        int m = deg - base; if (m > 64) m = 64;
        int sidx = (lane < m) ? srcs[p0 + base + lane] : 0;
        int e = 0;
        for (; e + 8 <= m; e += 8) {
            unsigned int v[8];
#pragma unroll
            for (int u = 0; u < 8; u++) {
                int s = __shfl(sidx, e + u);
                v[u] = *(const unsigned int*)(hb + (size_t)s * 128 + lane * 2);
            }
#pragma unroll
            for (int u = 0; u < 8; u++) {
                ax += __uint_as_float(v[u] << 16);
                ay += __uint_as_float(v[u] & 0xffff0000u);
            }
        }
        for (; e < m; e++) {
            int s = __shfl(sidx, e);
            unsigned int v = *(const unsigned int*)(hb + (size_t)s * 128 + lane * 2);
            ax += __uint_as_float(v << 16);
            ay += __uint_as_float(v & 0xffff0000u);
        }
    }
    float inv = 1.0f / (float)(deg > 1 ? deg : 1);
    unsigned int o = (unsigned int)f32_to_bf16_rne(ax * inv)
                   | ((unsigned int)f32_to_bf16_rne(ay * inv) << 16);
    *(unsigned int*)(aggb + (size_t)node * 128 + lane * 2) = o;
}

// ---------------- fused SAGE update via split-bf16 MFMA ----------------
// LAYER=0: hsrc is fp32 x (hi/lo split); LAYER=1: hsrc is bf16 h0b. agg is bf16.
template <int LAYER, bool FINAL>
__global__ __launch_bounds__(256, 2) void update_mfma(
    const unsigned short* __restrict__ aggb, const void* __restrict__ hsrc,
    const uint4* __restrict__ Wsw, const float* __restrict__ bias,
    unsigned short* __restrict__ hout,
    const float* __restrict__ Wh, const float* __restrict__ bh,
    float* __restrict__ logits, int n) {
    __shared__ uint4 Alds[2048];  // [mt(8)][kt(2)][plane(2)][lane(64)] 16B
    __shared__ uint4 Wlds[2048];  // [kt(2)][nt(8)][plane(2)][lane(64)] 16B
    const int tid = threadIdx.x;
    const int lane = tid & 63;
    const int w = tid >> 6;
    const int i0 = blockIdx.x * 128;

    f32x4 acc[2][8];
#pragma unroll
    for (int mt = 0; mt < 2; mt++)
#pragma unroll
        for (int nt = 0; nt < 8; nt++) acc[mt][nt] = (f32x4)0.f;

    const int r = tid >> 1;
    const int half = tid & 1;
    const int rg = i0 + r;
    const bool inb = rg < n;
    const int mt_s = r >> 4;
    const int lidx = r & 15;

    for (int c = 0; c < 4; c++) {
        const bool haslo = (LAYER == 0 && c >= 2);
        {
            const uint4* srcW = Wsw + (size_t)c * 2048;
#pragma unroll
            for (int g = 0; g < 8; g++) Wlds[g * 256 + tid] = srcW[g * 256 + tid];
        }
        {
            unsigned short hiA[32], loA[32];
            if (LAYER == 0 && c >= 2) {
                const float4* s4 = (const float4*)((const float*)hsrc + (size_t)rg * 128 +
                                                   (c - 2) * 64 + half * 32);
#pragma unroll
                for (int q = 0; q < 8; q++) {
                    float4 f = inb ? s4[q] : make_float4(0.f, 0.f, 0.f, 0.f);
                    float vv[4] = {f.x, f.y, f.z, f.w};
#pragma unroll
                    for (int e = 0; e < 4; e++) {
                        unsigned short h = f32_to_bf16_rne(vv[e]);
                        hiA[q * 4 + e] = h;
                        loA[q * 4 + e] = f32_to_bf16_rne(vv[e] - bf16_bits_to_f32(h));
                    }
                }
            } else {
                const unsigned short* bsrc = (c < 2) ? aggb : (const unsigned short*)hsrc;
                int cc = (c < 2) ? c : c - 2;
                const uint4* s4 = (const uint4*)(bsrc + (size_t)rg * 128 + cc * 64 + half * 32);
#pragma unroll
                for (int q = 0; q < 4; q++) {
                    uint4 u = inb ? s4[q] : make_uint4(0, 0, 0, 0);
                    unsigned int uu[4] = {u.x, u.y, u.z, u.w};
#pragma unroll
                    for (int e = 0; e < 4; e++) {
                        hiA[q * 8 + e * 2 + 0] = (unsigned short)(uu[e] & 0xffffu);
                        hiA[q * 8 + e * 2 + 1] = (unsigned short)(uu[e] >> 16);
                    }
                }
            }
            unsigned int baseHi = ((mt_s * 2 + half) * 2 + 0) * 64;
#pragma unroll
            for (int g2 = 0; g2 < 4; g2++)
                Alds[baseHi + lidx + 16 * g2] = pack8(&hiA[g2 * 8]);
            if (haslo) {
#pragma unroll
                for (int g2 = 0; g2 < 4; g2++)
                    Alds[baseHi + 64 + lidx + 16 * g2] = pack8(&loA[g2 * 8]);
            }
        }
        __syncthreads();
#pragma unroll
        for (int kt = 0; kt < 2; kt++) {
            bf16x8 a0h = *(const bf16x8*)&Alds[(((w * 2 + 0) * 2 + kt) * 2 + 0) * 64 + lane];
            bf16x8 a1h = *(const bf16x8*)&Alds[(((w * 2 + 1) * 2 + kt) * 2 + 0) * 64 + lane];
            bf16x8 a0l, a1l;
            if (haslo) {
                a0l = *(const bf16x8*)&Alds[(((w * 2 + 0) * 2 + kt) * 2 + 1) * 64 + lane];
                a1l = *(const bf16x8*)&Alds[(((w * 2 + 1) * 2 + kt) * 2 + 1) * 64 + lane];
            }
#pragma unroll
            for (int nt = 0; nt < 8; nt++) {
                bf16x8 bhv = *(const bf16x8*)&Wlds[((kt * 8 + nt) * 2 + 0) * 64 + lane];
                bf16x8 blv = *(const bf16x8*)&Wlds[((kt * 8 + nt) * 2 + 1) * 64 + lane];
                acc[0][nt] = __builtin_amdgcn_mfma_f32_16x16x32_bf16(a0h, bhv, acc[0][nt], 0, 0, 0);
                acc[0][nt] = __builtin_amdgcn_mfma_f32_16x16x32_bf16(a0h, blv, acc[0][nt], 0, 0, 0);
                acc[1][nt] = __builtin_amdgcn_mfma_f32_16x16x32_bf16(a1h, bhv, acc[1][nt], 0, 0, 0);
                acc[1][nt] = __builtin_amdgcn_mfma_f32_16x16x32_bf16(a1h, blv, acc[1][nt], 0, 0, 0);
                if (haslo) {
                    acc[0][nt] = __builtin_amdgcn_mfma_f32_16x16x32_bf16(a0l, bhv, acc[0][nt], 0, 0, 0);
                    acc[1][nt] = __builtin_amdgcn_mfma_f32_16x16x32_bf16(a1l, bhv, acc[1][nt], 0, 0, 0);
                }
            }
        }
        __syncthreads();
    }

    const int col = lane & 15;
    const int g4 = lane >> 4;
    float bcol[8];
#pragma unroll
    for (int nt = 0; nt < 8; nt++) bcol[nt] = bias[nt * 16 + col];
    if (!FINAL) {
#pragma unroll
        for (int mt = 0; mt < 2; mt++) {
            int nodeBase = i0 + (w * 2 + mt) * 16 + g4 * 4;
#pragma unroll
            for (int reg = 0; reg < 4; reg++) {
                int node = nodeBase + reg;
                if (node < n) {
#pragma unroll
                    for (int nt = 0; nt < 8; nt++) {
                        float v = acc[mt][nt][reg] + bcol[nt];
                        v = v > 0.f ? v : 0.f;
                        hout[(size_t)node * 128 + nt * 16 + col] = f32_to_bf16_rne(v);
                    }
                }
            }
        }
    } else {
        float whc[8];
#pragma unroll
        for (int nt = 0; nt < 8; nt++) whc[nt] = Wh[nt * 16 + col];
        float bhv = bh[0];
#pragma unroll
        for (int mt = 0; mt < 2; mt++) {
            int nodeBase = i0 + (w * 2 + mt) * 16 + g4 * 4;
#pragma unroll
            for (int reg = 0; reg < 4; reg++) {
                float s = 0.f;
#pragma unroll
                for (int nt = 0; nt < 8; nt++) {
                    float v = acc[mt][nt][reg] + bcol[nt];
                    v = v > 0.f ? v : 0.f;
                    s += v * whc[nt];
                }
                s += __shfl_xor(s, 1);
                s += __shfl_xor(s, 2);
                s += __shfl_xor(s, 4);
                s += __shfl_xor(s, 8);
                int node = nodeBase + reg;
                if (col == 0 && node < n) logits[node] = s + bhv;
            }
        }
    }
}

extern "C" void kernel_launch(void* const* d_in, const int* in_sizes, int n_in,
                              void* d_out, int out_size, void* d_ws, size_t ws_size,
                              hipStream_t stream) {
    const float* x   = (const float*)d_in[0];
    const int*   ei  = (const int*)d_in[1];
    const float* Wn0 = (const float*)d_in[2];
    const float* Wr0 = (const float*)d_in[3];
    const float* b0  = (const float*)d_in[4];
    const float* Wn1 = (const float*)d_in[5];
    const float* Wr1 = (const float*)d_in[6];
    const float* b1  = (const float*)d_in[7];
    const float* Wh  = (const float*)d_in[8];
    const float* bh  = (const float*)d_in[9];
    float* logits = (float*)d_out;

    int N = in_sizes[0] / 128;
    int E = in_sizes[1] / 2;
    const int* src = ei;
    const int* dst = ei + E;

    char* ws = (char*)d_ws;
    size_t cur = 0;
    auto alloc = [&](size_t bytes) -> void* {
        void* p = ws + cur;
        cur += (bytes + 255) & ~(size_t)255;
        return p;
    };
    int NB = (N + 2047) / 2048;
    int* cnt   = (int*)alloc((size_t)(N + 16) * 4);  // + 16 work-steal cursors
    int* off   = (int*)alloc((size_t)(N + 1) * 4);
    int* pos   = (int*)alloc((size_t)N * 4);
    int* bsums = (int*)alloc((size_t)NB * 4);
    int* bbase = (int*)alloc((size_t)NB * 4);
    int* srcs  = (int*)alloc((size_t)E * 4);
    unsigned short* xb  = (unsigned short*)alloc((size_t)N * 128 * 2);
    unsigned short* h0b = (unsigned short*)alloc((size_t)N * 128 * 2);
    unsigned short* agb = (unsigned short*)alloc((size_t)N * 128 * 2);
    uint4* Wsw0 = (uint4*)alloc(131072);
    uint4* Wsw1 = (uint4*)alloc(131072);
    (void)ws_size; (void)n_in; (void)out_size;

    int* curs_deg = cnt + N;
    int* curs_bkt = cnt + N + 8;
    int gN0 = (N + 16 + 255) / 256;
    int gN = (N + 255) / 256;

    // CSR build (XCD-pinned slices with work-stealing)
    hipLaunchKernelGGL(zero_int,    dim3(gN0),  dim3(256), 0, stream, cnt, N + 16);
    hipLaunchKernelGGL(degree_xcd,  dim3(2048), dim3(256), 0, stream, dst, cnt, curs_deg, E);
    hipLaunchKernelGGL(scan1_kernel, dim3(NB),  dim3(256), 0, stream, cnt, off, bsums, N);
    hipLaunchKernelGGL(scan2_kernel, dim3(1),   dim3(64),  0, stream, bsums, bbase, NB, off + N);
    hipLaunchKernelGGL(scan3_kernel, dim3(gN),  dim3(256), 0, stream, off, pos, bbase, N);
    hipLaunchKernelGGL(bucket_xcd,  dim3(2048), dim3(256), 0, stream, src, dst, pos, srcs, curs_bkt, E);

    // Precision prep
    int n4 = N * 32;
    hipLaunchKernelGGL(cvt_bf16_kernel, dim3((n4 + 255) / 256), dim3(256), 0, stream,
                       (const float4*)x, (ushort4*)xb, n4);
    hipLaunchKernelGGL(swizzle_w_kernel, dim3(16), dim3(256), 0, stream, Wn0, Wr0, Wsw0);
    hipLaunchKernelGGL(swizzle_w_kernel, dim3(16), dim3(256), 0, stream, Wn1, Wr1, Wsw1);

    int gAgg = (N + 3) / 4;
    int gUpd = (N + 127) / 128;

    // Layer 0
    hipLaunchKernelGGL(agg_kernel, dim3(gAgg), dim3(256), 0, stream, xb, off, srcs, agb, N);
    hipLaunchKernelGGL((update_mfma<0, false>), dim3(gUpd), dim3(256), 0, stream,
                       agb, (const void*)x, Wsw0, b0, h0b, nullptr, nullptr, nullptr, N);
    // Layer 1 + fused head
    hipLaunchKernelGGL(agg_kernel, dim3(gAgg), dim3(256), 0, stream, h0b, off, srcs, agb, N);
    hipLaunchKernelGGL((update_mfma<1, true>), dim3(gUpd), dim3(256), 0, stream,
                       agb, (const void*)h0b, Wsw1, b1, nullptr, Wh, bh, logits, N);
}